// Round 7
// baseline (773.395 us; speedup 1.0000x reference)
//
#include <hip/hip_runtime.h>
#include <hip/hip_bf16.h>
#include <math.h>

#define NB 64
#define HW 4096
#define CI 256
#define CO 256
#define NE 8

typedef __bf16 bf16x8 __attribute__((ext_vector_type(8)));
typedef __bf16 bf16x4 __attribute__((ext_vector_type(4)));
typedef float  f32x4  __attribute__((ext_vector_type(4)));

// ---------------- pooling: sum over H*W per (b,c) ----------------
// grid 1024 = 64 b * 16 chunks, block 256. float4 loads, LDS reduce, atomicAdd.
__global__ void pool_kernel(const float* __restrict__ x, float* __restrict__ pooled) {
    int blk = blockIdx.x;
    int b = blk >> 4, chunk = blk & 15;
    int t = threadIdx.x;
    int c4 = t & 63;       // float4 channel group (channels c4*4..+3)
    int rg = t >> 6;       // row subgroup 0..3
    const float4* xp = (const float4*)x;
    size_t base = ((size_t)b * HW + (size_t)chunk * 256) * (CI / 4) + c4;
    float4 acc = make_float4(0.f, 0.f, 0.f, 0.f);
    for (int r = rg; r < 256; r += 4) {
        float4 v = xp[base + (size_t)r * (CI / 4)];
        acc.x += v.x; acc.y += v.y; acc.z += v.z; acc.w += v.w;
    }
    __shared__ float4 red[256];
    red[t] = acc;
    __syncthreads();
    if (t < 64) {
        float4 a = red[t], b2 = red[t + 64], c = red[t + 128], d = red[t + 192];
        float s0 = a.x + b2.x + c.x + d.x;
        float s1 = a.y + b2.y + c.y + d.y;
        float s2 = a.z + b2.z + c.z + d.z;
        float s3 = a.w + b2.w + c.w + d.w;
        atomicAdd(&pooled[b * CI + t * 4 + 0], s0);
        atomicAdd(&pooled[b * CI + t * 4 + 1], s1);
        atomicAdd(&pooled[b * CI + t * 4 + 2], s2);
        atomicAdd(&pooled[b * CI + t * 4 + 3], s3);
    }
}

// ---------------- W prep: W[e][k][n] f32 -> Wt[e][n][k] bf16 ----------------
// grid 128 = 8 e * 4 kt * 4 nt, block 256. LDS transpose tile (pad 65 -> no conflicts).
__global__ void wprep_kernel(const float* __restrict__ W, __bf16* __restrict__ Wt) {
    __shared__ float tile[64][65];
    int e  = blockIdx.x >> 4;
    int kt = (blockIdx.x >> 2) & 3;
    int nt = blockIdx.x & 3;
    for (int i = threadIdx.x; i < 4096; i += 256) {
        int r = i >> 6, c = i & 63;      // r = k-local, c = n-local
        tile[r][c] = W[((size_t)(e * 256 + kt * 64 + r)) * 256 + nt * 64 + c];
    }
    __syncthreads();
    for (int i = threadIdx.x; i < 4096; i += 256) {
        int r = i >> 6, c = i & 63;      // r = n-local, c = k-local
        Wt[((size_t)(e * 256 + nt * 64 + r)) * 256 + kt * 64 + c] = (__bf16)tile[c][r];
    }
}

// ---------------- gating: logits -> argmax -> counts -> lb_loss ----------------
// 1 block, 64 threads (one wave), thread b handles sample b.
__global__ void gate_kernel(const float* __restrict__ pooled,
                            const float* __restrict__ gate_W,
                            const float* __restrict__ gate_b,
                            int* __restrict__ eidx,
                            float* __restrict__ lb_out) {
    int b = threadIdx.x;  // 0..63
    float logit[NE];
#pragma unroll
    for (int e = 0; e < NE; ++e) logit[e] = gate_b[e];
    for (int c = 0; c < CI; ++c) {
        float p = pooled[b * CI + c] * (1.0f / 4096.0f);
#pragma unroll
        for (int e = 0; e < NE; ++e) logit[e] += p * gate_W[c * NE + e];
    }
    int best = 0; float bv = logit[0];
#pragma unroll
    for (int e = 1; e < NE; ++e) {
        if (logit[e] > bv) { bv = logit[e]; best = e; }  // strict > keeps first (jnp.argmax)
    }
    eidx[b] = best;
    float u[NE]; float s = 0.f;
#pragma unroll
    for (int e = 0; e < NE; ++e) {
        unsigned long long m = __ballot(best == e);
        u[e] = (float)__popcll(m) * (1.0f / 64.0f) + 1e-6f;
        s += u[e];
    }
    if (b == 0) {
        float lb = 0.f;
#pragma unroll
        for (int e = 0; e < NE; ++e) {
            float ue = u[e] / s;
            lb += ue * (logf(ue) - logf(0.125f));
        }
        *lb_out = lb;
    }
}

// ---------------- main GEMM: out[b] = x[b] @ W[e_b] + bias[e_b] ----------------
// grid 2048 = 64 b * 32 mtiles(128 rows). 4 waves; wave w owns cols [w*64, w*64+64).
// NO LDS, NO BARRIERS: A-fragments loaded straight from global f32 (16 rows x
// 128 B contiguous per row per instr -> L1-served for waves 1-3), converted to
// bf16 in regs. B-fragments from L2-resident pre-transposed Wt. Latency hidden
// by ILP (loads hoisted over MFMA, unroll 2) + TLP (no barrier drains).
__global__ void __launch_bounds__(256)
moe_gemm(const float* __restrict__ x, const __bf16* __restrict__ Wt,
         const float* __restrict__ bias, const int* __restrict__ eidx,
         float* __restrict__ out) {
    int mt = blockIdx.x & 31;
    int b  = blockIdx.x >> 5;
    int e  = eidx[b];
    int tid = threadIdx.x;
    int w = tid >> 6, lane = tid & 63;
    int l15 = lane & 15, l4 = lane >> 4;
    int hw0 = mt * 128;

    // init acc with bias (C/D layout: col = lane&15, row = (lane>>4)*4 + reg)
    f32x4 acc[8][4];
#pragma unroll
    for (int n = 0; n < 4; ++n) {
        float bv = bias[e * CO + w * 64 + n * 16 + l15];
        f32x4 t = {bv, bv, bv, bv};
#pragma unroll
        for (int m = 0; m < 8; ++m) acc[m][n] = t;
    }

    // A: lane reads rows hw0 + m*16 + l15, k-bytes [ks*32 + l4*8 .. +8) as 2 float4
    const float4* xp = (const float4*)x;
    size_t xrow = ((size_t)b * HW + hw0 + l15) * (CI / 4) + l4 * 2;  // float4 units
    // B: Wt[e][n][k], frag n at row (e*256 + w*64 + n*16 + l15), k = ks*32 + l4*8
    const bf16x8* wp = (const bf16x8*)Wt;
    int wbase = (e * 256 + w * 64 + l15) * 32 + l4;

#pragma unroll 2
    for (int ks = 0; ks < 8; ++ks) {
        bf16x8 bf[4];
#pragma unroll
        for (int n = 0; n < 4; ++n) bf[n] = wp[wbase + n * 512 + ks * 4];

        bf16x8 af[8];
#pragma unroll
        for (int m = 0; m < 8; ++m) {
            size_t idx = xrow + (size_t)(m * 16) * (CI / 4) + ks * 8;
            float4 v0 = xp[idx];
            float4 v1 = xp[idx + 1];
            af[m] = bf16x8{(__bf16)v0.x, (__bf16)v0.y, (__bf16)v0.z, (__bf16)v0.w,
                           (__bf16)v1.x, (__bf16)v1.y, (__bf16)v1.z, (__bf16)v1.w};
        }

#pragma unroll
        for (int m = 0; m < 8; ++m)
#pragma unroll
            for (int n = 0; n < 4; ++n)
                acc[m][n] = __builtin_amdgcn_mfma_f32_16x16x32_bf16(af[m], bf[n], acc[m][n], 0, 0, 0);
    }

    // epilogue: 16 lanes x 4B contiguous per (row-group, n) -> 64B segments
    size_t obase = ((size_t)b * HW + hw0) * CO;
#pragma unroll
    for (int m = 0; m < 8; ++m)
#pragma unroll
        for (int n = 0; n < 4; ++n)
#pragma unroll
            for (int r = 0; r < 4; ++r) {
                int row = m * 16 + l4 * 4 + r;
                int col = w * 64 + n * 16 + l15;
                out[obase + (size_t)row * CO + col] = acc[m][n][r];
            }
}

extern "C" void kernel_launch(void* const* d_in, const int* in_sizes, int n_in,
                              void* d_out, int out_size, void* d_ws, size_t ws_size,
                              hipStream_t stream) {
    const float* x      = (const float*)d_in[0];
    const float* W      = (const float*)d_in[1];
    const float* bias   = (const float*)d_in[2];
    const float* gate_W = (const float*)d_in[3];
    const float* gate_b = (const float*)d_in[4];
    float* out = (float*)d_out;

    char* ws = (char*)d_ws;
    __bf16* Wt     = (__bf16*)ws;                          // 1 MiB
    float*  pooled = (float*)(ws + (1 << 20));             // 64 KiB
    int*    eidx   = (int*)(ws + (1 << 20) + (64 << 10));  // 256 B
    float*  lb_out = out + (size_t)NB * HW * CO;           // last output element

    hipMemsetAsync(pooled, 0, NB * CI * sizeof(float), stream);
    pool_kernel<<<1024, 256, 0, stream>>>(x, pooled);
    wprep_kernel<<<128, 256, 0, stream>>>(W, Wt);
    gate_kernel<<<1, 64, 0, stream>>>(pooled, gate_W, gate_b, eidx, lb_out);
    moe_gemm<<<2048, 256, 0, stream>>>(x, Wt, bias, eidx, out);
}

// Round 8
// 548.531 us; speedup vs baseline: 1.4099x; 1.4099x over previous
//
#include <hip/hip_runtime.h>
#include <hip/hip_bf16.h>
#include <math.h>

#define NB 64
#define HW 4096
#define CI 256
#define CO 256
#define NE 8

typedef __bf16 bf16x8 __attribute__((ext_vector_type(8)));
typedef __bf16 bf16x4 __attribute__((ext_vector_type(4)));
typedef float  f32x4  __attribute__((ext_vector_type(4)));

// ---------------- pass 1: pool + f32->bf16 cvt + swizzled re-layout ----------------
// grid 1024 = 64 b * 16 chunks(256 rows), block 256 (4 waves).
// Per wave-iter: read one full row (64 lanes x float4 = 1 KB coalesced),
// write the row as bf16 (64 lanes x 8 B = 512 B) with 16B-slot XOR swizzle
// (slot ^= hw&7) so the GEMM's LDS ds_read_b128 is bank-conflict-free.
__global__ void pool_cvt_kernel(const float* __restrict__ x, __bf16* __restrict__ xb,
                                float* __restrict__ pooled) {
    int blk = blockIdx.x;
    int b = blk >> 4, chunk = blk & 15;
    int t = threadIdx.x;
    int l = t & 63;        // lane: float4 channel group (channels 4l..4l+3)
    int rg = t >> 6;       // row subgroup 0..3
    const float4* xp = (const float4*)x;
    int slot0 = l >> 1;            // 16B slot in un-swizzled row
    int intra = (l & 1) * 8;       // byte within slot
    float4 acc = make_float4(0.f, 0.f, 0.f, 0.f);
    for (int r = rg; r < 256; r += 4) {
        int hw = chunk * 256 + r;
        size_t row = (size_t)b * HW + hw;
        float4 v = xp[row * (CI / 4) + l];
        acc.x += v.x; acc.y += v.y; acc.z += v.z; acc.w += v.w;
        int slot = slot0 ^ (hw & 7);
        char* dst = (char*)xb + row * 512 + slot * 16 + intra;
        bf16x4 h = {(__bf16)v.x, (__bf16)v.y, (__bf16)v.z, (__bf16)v.w};
        *(bf16x4*)dst = h;
    }
    __shared__ float4 red[256];
    red[t] = acc;
    __syncthreads();
    if (t < 64) {
        float4 a = red[t], b2 = red[t + 64], c = red[t + 128], d = red[t + 192];
        atomicAdd(&pooled[b * CI + t * 4 + 0], a.x + b2.x + c.x + d.x);
        atomicAdd(&pooled[b * CI + t * 4 + 1], a.y + b2.y + c.y + d.y);
        atomicAdd(&pooled[b * CI + t * 4 + 2], a.z + b2.z + c.z + d.z);
        atomicAdd(&pooled[b * CI + t * 4 + 3], a.w + b2.w + c.w + d.w);
    }
}

// ---------------- W prep: W[e][k][n] f32 -> fragment-ordered bf16 ----------------
// Wt_frag[e][nf(16)][ks(8)][lane(64)][8 bf16]: lane holds col nf*16+(l&15),
// k = ks*32 + (l>>4)*8 .. +8  -> GEMM B-load is base + lane*16, fully linear.
// grid 128 = 8 e * 16 nf, block 256.
__global__ void wprep_kernel(const float* __restrict__ W, __bf16* __restrict__ Wf) {
    __shared__ float slab[256][16];   // [k][n-local]
    int e  = blockIdx.x >> 4;
    int nf = blockIdx.x & 15;
    int t = threadIdx.x;              // = k
    const float* src = W + ((size_t)(e * 256 + t)) * 256 + nf * 16;
#pragma unroll
    for (int j = 0; j < 16; ++j) slab[t][j] = src[j];
    __syncthreads();
    int lane = t & 63;
    int col = lane & 15;
#pragma unroll
    for (int h = 0; h < 2; ++h) {
        int ks = (t >> 6) + h * 4;
        int kb = ks * 32 + (lane >> 4) * 8;
        bf16x8 v;
#pragma unroll
        for (int q = 0; q < 8; ++q) v[q] = (__bf16)slab[kb + q][col];
        *(bf16x8*)(Wf + ((size_t)((e * 16 + nf) * 8 + ks) * 64 + lane) * 8) = v;
    }
}

// ---------------- gating: logits -> argmax -> counts -> lb_loss ----------------
__global__ void gate_kernel(const float* __restrict__ pooled,
                            const float* __restrict__ gate_W,
                            const float* __restrict__ gate_b,
                            int* __restrict__ eidx,
                            float* __restrict__ lb_out) {
    int b = threadIdx.x;  // 0..63
    float logit[NE];
#pragma unroll
    for (int e = 0; e < NE; ++e) logit[e] = gate_b[e];
    for (int c = 0; c < CI; ++c) {
        float p = pooled[b * CI + c] * (1.0f / 4096.0f);
#pragma unroll
        for (int e = 0; e < NE; ++e) logit[e] += p * gate_W[c * NE + e];
    }
    int best = 0; float bv = logit[0];
#pragma unroll
    for (int e = 1; e < NE; ++e) {
        if (logit[e] > bv) { bv = logit[e]; best = e; }  // strict > == jnp.argmax
    }
    eidx[b] = best;
    float u[NE]; float s = 0.f;
#pragma unroll
    for (int e = 0; e < NE; ++e) {
        unsigned long long m = __ballot(best == e);
        u[e] = (float)__popcll(m) * (1.0f / 64.0f) + 1e-6f;
        s += u[e];
    }
    if (b == 0) {
        float lb = 0.f;
#pragma unroll
        for (int e = 0; e < NE; ++e) {
            float ue = u[e] / s;
            lb += ue * (logf(ue) - logf(0.125f));
        }
        *lb_out = lb;
    }
}

// ---------------- main GEMM ----------------
// grid 2048 = 64 b * 32 mtiles(128 rows), 4 waves, wave w owns cols [w*64,+64).
// Stage full 128x256 bf16 A-tile (64 KB) via global_load_lds width=16 (linear
// dest; source rows pre-swizzled by pass 1). ONE barrier, then 8 unrolled
// K-steps: 4 linear 1KB B-loads (L2) + 8 swizzled conflict-free ds_read_b128
// + 32 MFMA. 2 blocks/CU (LDS 64KB), ~4096 outstanding stage loads.
__global__ void __launch_bounds__(256, 2)
moe_gemm(const __bf16* __restrict__ xb, const __bf16* __restrict__ Wf,
         const float* __restrict__ bias, const int* __restrict__ eidx,
         float* __restrict__ out) {
    __shared__ __align__(16) char At[65536];   // 128 rows x 512 B
    int mt = blockIdx.x & 31;
    int b  = blockIdx.x >> 5;
    int e  = eidx[b];
    int tid = threadIdx.x;
    int w = tid >> 6, lane = tid & 63;
    int l15 = lane & 15, l4 = lane >> 4;
    int hw0 = mt * 128;

    // stage A-tile: 64 wave-ops of 1 KB, async into LDS
    const char* src = (const char*)xb + ((size_t)b * HW + hw0) * 512;
#pragma unroll
    for (int i = 0; i < 16; ++i) {
        int blkoff = (i * 4 + w) * 1024;               // wave-uniform
        const char* g = src + blkoff + lane * 16;      // per-lane global
        __builtin_amdgcn_global_load_lds(
            (const __attribute__((address_space(1))) void*)g,
            (__attribute__((address_space(3))) void*)(At + blkoff), 16, 0, 0);
    }

    // init acc with bias (C/D: col = lane&15, row = (lane>>4)*4 + reg)
    f32x4 acc[8][4];
#pragma unroll
    for (int n = 0; n < 4; ++n) {
        float bv = bias[e * CO + w * 64 + n * 16 + l15];
        f32x4 tt = {bv, bv, bv, bv};
#pragma unroll
        for (int m = 0; m < 8; ++m) acc[m][n] = tt;
    }

    const bf16x8* wf = (const bf16x8*)(Wf + (size_t)e * 16 * 8 * 64 * 8);

    __syncthreads();   // drains vmcnt -> A-tile resident

#pragma unroll
    for (int ks = 0; ks < 8; ++ks) {
        bf16x8 bf[4];
#pragma unroll
        for (int n = 0; n < 4; ++n)
            bf[n] = wf[((w * 4 + n) * 8 + ks) * 64 + lane];
        bf16x8 af[8];
#pragma unroll
        for (int m = 0; m < 8; ++m) {
            int byte = (m * 16 + l15) * 512 + (((ks * 4 + l4) ^ (l15 & 7)) * 16);
            af[m] = *(const bf16x8*)(At + byte);
        }
#pragma unroll
        for (int m = 0; m < 8; ++m)
#pragma unroll
            for (int n = 0; n < 4; ++n)
                acc[m][n] = __builtin_amdgcn_mfma_f32_16x16x32_bf16(af[m], bf[n], acc[m][n], 0, 0, 0);
    }

    // epilogue: 64B segments per (row-group, n); 4 n-frags cover 256B/row
    size_t obase = ((size_t)b * HW + hw0) * CO;
#pragma unroll
    for (int m = 0; m < 8; ++m)
#pragma unroll
        for (int n = 0; n < 4; ++n)
#pragma unroll
            for (int r = 0; r < 4; ++r) {
                int row = m * 16 + l4 * 4 + r;
                int col = w * 64 + n * 16 + l15;
                out[obase + (size_t)row * CO + col] = acc[m][n][r];
            }
}

extern "C" void kernel_launch(void* const* d_in, const int* in_sizes, int n_in,
                              void* d_out, int out_size, void* d_ws, size_t ws_size,
                              hipStream_t stream) {
    const float* x      = (const float*)d_in[0];
    const float* W      = (const float*)d_in[1];
    const float* bias   = (const float*)d_in[2];
    const float* gate_W = (const float*)d_in[3];
    const float* gate_b = (const float*)d_in[4];
    float* out = (float*)d_out;

    char* ws = (char*)d_ws;
    __bf16* xb     = (__bf16*)ws;                                   // 128 MiB
    __bf16* Wf     = (__bf16*)(ws + (size_t)(128 << 20));           // 1 MiB
    float*  pooled = (float*)(ws + (size_t)(129 << 20));            // 64 KiB
    int*    eidx   = (int*)(ws + (size_t)(129 << 20) + (64 << 10)); // 256 B
    float*  lb_out = out + (size_t)NB * HW * CO;                    // last elem

    hipMemsetAsync(pooled, 0, NB * CI * sizeof(float), stream);
    pool_cvt_kernel<<<1024, 256, 0, stream>>>(x, xb, pooled);
    wprep_kernel<<<128, 256, 0, stream>>>(W, Wf);
    gate_kernel<<<1, 64, 0, stream>>>(pooled, gate_W, gate_b, eidx, lb_out);
    moe_gemm<<<2048, 256, 0, stream>>>(xb, Wf, bias, eidx, out);
}